// Round 3
// baseline (114.470 us; speedup 1.0000x reference)
//
#include <hip/hip_runtime.h>
#include <stdint.h>

// out[b,i,j] = conv3x3_valid(inp, c*k)[b,i,j]
// c = vt(I=1) from the LIF scan (linear in I; spike/clamp provably inactive
// since I < 9 < 14 for all 1000 steps). c folded into the taps.
//
// R7: ring-buffer persistent blocks -- attack TRAFFIC + RESIDENCY, not sync.
// R4/R5/R6 (three different sync schedules) all ~31us kernel -> sync is not
// the limiter. Changes:
//  (1) Each block's 4 jobs are now CONSECUTIVE strips of one batch; LDS is a
//      ring of 18 rows. Per iteration only the 8 NEW rows are staged (the 2
//      halo rows are already resident from the previous job): read traffic
//      83.9 -> 71.3 MB (-15%), stage insts 5 -> 4 per iter.
//  (2) LDS 36864 B (was 40960x... 2x20480=40960: 4 blocks/CU required EXACT
//      160KiB fit -- any runtime rounding -> 3 blocks/CU -> 256-block second
//      wave (+33% kernel) which would explain R5/R6 nulling). Ring leaves
//      16KB slack; __launch_bounds__(256,4) pins 4 waves/EU.
// Counted-vmcnt discipline kept (exact & uniform): queue at iter-it wait is
// [stage(it):4or5][stores(it-1):8][stage(it+1):4] -> vmcnt 4/12/12/8.
// Ring=18 makes stage(it+1) slot-disjoint from compute(it)'s 10 rows (WAR
// safe pre-barrier); stage(it+2) fenced by the end-of-iter barrier.
// Bottom group (sgrp 15) starts at row 478: rows 478/479 double-written with
// identical expression trees (R6-validated trick) -> stores unpredicated.

#define RING   18
#define TILE_F (RING * 512)      // 9216 floats = 36864 B
#define GRID_X 1024              // 64 batches x 16 strip-groups, 4 jobs each

__device__ static inline void async_copy16(const float* gsrc, float* ldst) {
    __builtin_amdgcn_global_load_lds(
        (const __attribute__((address_space(1))) void*)gsrc,
        (__attribute__((address_space(3))) void*)ldst, 16, 0, 0);
}

__global__ __launch_bounds__(256, 4) void snn_conv_ring_kernel(
    const float* __restrict__ inp, const float* __restrict__ kw,
    float* __restrict__ out, float c)
{
    __shared__ float tile[TILE_F];

    const int tid = threadIdx.x;
    const int tp  = tid & 127;     // column group: output cols 4tp..4tp+3
    const int ty  = tid >> 7;      // row group 0/1 (wave-uniform)
    const int j   = tp << 2;
    const int r0  = ty << 2;       // job-relative first out row (0 or 4)

    const int bid   = (int)blockIdx.x;
    const int batch = bid >> 4;
    const int sgrp  = bid & 15;
    // group covers output rows B0..B0+31; sgrp 15 starts at 478 (2-row
    // overlap with sgrp 14; bit-identical double-writes) so all 32 rows and
    // all 34 input rows (478..511) are in-bounds -> no predication anywhere.
    const int B0    = (sgrp < 15) ? (sgrp << 5) : 478;

    const float* gbase = inp + (size_t)batch * 262144 + (size_t)B0 * 512;
    float*       obase = out + (size_t)batch * 260100 + (size_t)B0 * 510;

    // taps (uniform -> scalar SMEM loads, lgkmcnt not vmcnt), c folded
    const float k00 = kw[0]*c, k01 = kw[1]*c, k02 = kw[2]*c;
    const float k10 = kw[3]*c, k11 = kw[4]*c, k12 = kw[5]*c;
    const float k20 = kw[6]*c, k21 = kw[7]*c, k22 = kw[8]*c;

    // stage `2*NI` group-relative input rows [ROW0, ROW0+2*NI) into ring
    // slots [SLOT0, SLOT0+2*NI): contiguous in BOTH global and LDS.
#define STAGE(SLOT0, ROW0, NI)                                         \
    _Pragma("unroll")                                                  \
    for (int r_ = 0; r_ < (NI); ++r_) {                                \
        int fo_ = (r_ * 256 + tid) * 4;                                \
        async_copy16(gbase + (ROW0) * 512 + fo_,                       \
                     &tile[(SLOT0) * 512 + fo_]);                      \
    }

    STAGE(0, 0, 5);                   // prologue: 10 rows -> slots 0..9
    asm volatile("" ::: "memory");    // keep stage queues program-ordered

    float x0, x1, x2, x3, x4, x5;
    // ring read: slot = (S + ir) mod 18, S compile-time after unroll.
    // +4 halo b64 may cross a slot boundary (garbage, feeds only o[2]/o[3]
    // of tp==127 which are never stored); clamp keeps slot 17 in-bounds.
#define LOADX(S, ir)                                                   \
    {   int rr_ = (S) + (ir); if (rr_ >= RING) rr_ -= RING;            \
        float4 _a = *(const float4*)(&tile[rr_ * 512 + j]);            \
        float2 _h = *(const float2*)(&tile[min(rr_ * 512 + j + 4,      \
                                               TILE_F - 2)]);          \
        x0=_a.x; x1=_a.y; x2=_a.z; x3=_a.w; x4=_h.x; x5=_h.y; }

#pragma unroll
    for (int it = 0; it < 4; ++it) {
        const int S = (8 * it) % RING;              // 0,8,16,6  (folded)
        if (it < 3) {
            // next job's 8 NEW rows: group rows 8it+10..8it+17
            STAGE((8 * it + 10) % RING, 8 * it + 10, 4);   // slots 10,0,8
        }
        // Drain stage(it) only; stores(it-1) + stage(it+1) stay in flight.
        if (it == 0)      asm volatile("s_waitcnt vmcnt(4)"  ::: "memory");
        else if (it < 3)  asm volatile("s_waitcnt vmcnt(12)" ::: "memory");
        else              asm volatile("s_waitcnt vmcnt(8)"  ::: "memory");
        __builtin_amdgcn_s_barrier();               // raw: no vmcnt(0) drain
        asm volatile("" ::: "memory");

        // ---- compute job it: rolling vertical h-sums over 6 LDS rows ----
        float a2[4], a1[4], o[4];
        LOADX(S, r0);
        a2[0] = k00*x0 + k01*x1 + k02*x2;
        a2[1] = k00*x1 + k01*x2 + k02*x3;
        a2[2] = k00*x2 + k01*x3 + k02*x4;
        a2[3] = k00*x3 + k01*x4 + k02*x5;
        LOADX(S, r0 + 1);
        // same expression shapes as the loop body (bit-identical overlap rows)
        a1[0] = k00*x0 + k01*x1 + k02*x2;  a2[0] = a2[0] + k10*x0 + k11*x1 + k12*x2;
        a1[1] = k00*x1 + k01*x2 + k02*x3;  a2[1] = a2[1] + k10*x1 + k11*x2 + k12*x3;
        a1[2] = k00*x2 + k01*x3 + k02*x4;  a2[2] = a2[2] + k10*x2 + k11*x3 + k12*x4;
        a1[3] = k00*x3 + k01*x4 + k02*x5;  a2[3] = a2[3] + k10*x3 + k11*x4 + k12*x5;

#pragma unroll
        for (int r = 0; r < 4; ++r) {
            LOADX(S, r0 + r + 2);
            o[0] = a2[0] + k20*x0 + k21*x1 + k22*x2;
            o[1] = a2[1] + k20*x1 + k21*x2 + k22*x3;
            o[2] = a2[2] + k20*x2 + k21*x3 + k22*x4;
            o[3] = a2[3] + k20*x3 + k21*x4 + k22*x5;

            // group-relative out row 8it+r0+r in 0..31 -> always valid
            float* q = obase + (size_t)(8 * it + r0 + r) * 510 + j;
            // Uniform store count: 2 x float2 per row in EVERY wave (the
            // tp<127 exec mask is never all-zero -> inst always issues).
            *(float2*)q = make_float2(o[0], o[1]);
            if (tp < 127) *(float2*)(q + 2) = make_float2(o[2], o[3]);

            a2[0] = a1[0] + k10*x0 + k11*x1 + k12*x2;
            a2[1] = a1[1] + k10*x1 + k11*x2 + k12*x3;
            a2[2] = a1[2] + k10*x2 + k11*x3 + k12*x4;
            a2[3] = a1[3] + k10*x3 + k11*x4 + k12*x5;
            a1[0] = k00*x0 + k01*x1 + k02*x2;
            a1[1] = k00*x1 + k01*x2 + k02*x3;
            a1[2] = k00*x2 + k01*x3 + k02*x4;
            a1[3] = k00*x3 + k01*x4 + k02*x5;
        }

        asm volatile("" ::: "memory");
        __builtin_amdgcn_s_barrier();   // WAR: reads of this job's slots done
        asm volatile("" ::: "memory");  //      before next iter stages over them
    }
#undef LOADX
#undef STAGE
}

extern "C" void kernel_launch(void* const* d_in, const int* in_sizes, int n_in,
                              void* d_out, int out_size, void* d_ws, size_t ws_size,
                              hipStream_t stream) {
    (void)in_sizes; (void)n_in; (void)d_ws; (void)ws_size; (void)out_size;
    const float* inp = (const float*)d_in[0];
    const float* kw  = (const float*)d_in[1];
    float* out = (float*)d_out;

    // Closed-form LIF scan with I = 1 (double precision; exact by linearity).
    double v = 0.0;
    v = v + (3000.0 * 1.0 - v) / 30000.0 * 0.01;   // = 0.001
    double vt = v;
    for (int i = 0; i < 999; ++i) {
        v  = v + (3000.0 - v) / 30000.0 * 0.01;
        vt = (v + vt) / 1000.0;
    }
    float c = (float)vt;   // ~0.99983...

    dim3 block(256, 1, 1);
    dim3 grid(GRID_X, 1, 1);   // 1024 blocks x 4 consecutive-strip jobs
    hipLaunchKernelGGL(snn_conv_ring_kernel, grid, block, 0, stream,
                       inp, kw, out, c);
}